// Round 10
// baseline (242.583 us; speedup 1.0000x reference)
//
#include <hip/hip_runtime.h>
#include <hip/hip_bf16.h>

// WindowAttention (Swin) split pipeline for MI355X, round 10:
//   K1 qkv:  per-window 3-pass GEMM (roll fused on load). K/Q passes use swapped
//            operands (C^T = W·X^T) so each lane holds 4 consecutive n -> packed
//            8B stores into Qg/Kg [bw][49][192]. V pass normal -> packed 8B into
//            VTg [bw][192][64].
//   K2 attn: per-(window,head), zero-LDS, zero-barrier, lane-local softmax -> O2
//   K3 proj: per-window GEMM, inverse roll on store -> out
// bf16 MFMA, f32 accum. Fragment layout (gfx950, verified r2-r9):
//   A (16x32): lane l holds A[l&15][8*(l>>4)+j]   B (32x16): lane l holds B[8*(l>>4)+j][l&15]
//   C/D: lane l reg r -> C[4*(l>>4)+r][l&15]

typedef __bf16 bf16x8 __attribute__((ext_vector_type(8)));
typedef __bf16 bf16x4 __attribute__((ext_vector_type(4)));
typedef float f32x4 __attribute__((ext_vector_type(4)));
using bf = __bf16;

#define MFMA16(a, b, c) __builtin_amdgcn_mfma_f32_16x16x32_bf16((a), (b), (c), 0, 0, 0)

static constexpr float kNEG = -1000000000.0f;
static constexpr float kScale = 0.17677669529663687f;  // 32^-0.5

// workspace layout (bytes)
static constexpr size_t OFF_WQKVT = 0;                      // bf16 [576][192]
static constexpr size_t OFF_WOUTT = 221184;                 // bf16 [192][192]
static constexpr size_t OFF_TBLBF = 294912;                 // bf16 [4][49][68]
static constexpr size_t OFF_QG    = 321568;                 // bf16 [2048][49][192]
static constexpr size_t OFF_KG    = OFF_QG + 38535168ull;   // bf16 [2048][49][192]
static constexpr size_t OFF_VT    = OFF_KG + 38535168ull;   // bf16 [2048][192][64]
static constexpr size_t OFF_O2    = OFF_VT + 50331648ull;   // bf16 [2048][49][192]

static constexpr int VT_STR   = 64;    // V^T row stride (t up to 63 must fit)
static constexpr int X_STRIDE = 200;   // K1 LDS x-window stride
static constexpr int O_STRIDE = 200;   // K3 LDS O stride

__device__ __forceinline__ unsigned pack2(float a, float b) {
  union { bf h[2]; unsigned u; } cv;
  cv.h[0] = (bf)a; cv.h[1] = (bf)b;
  return cv.u;
}

// ---------------- K0: weight transposes + bf16 bias/mask tables ----------------
__global__ void prep_kernel(const float* __restrict__ wqkv, const float* __restrict__ wout,
                            const float* __restrict__ pos, char* __restrict__ ws) {
  bf* wqkvT = (bf*)(ws + OFF_WQKVT);
  bf* woutT = (bf*)(ws + OFF_WOUTT);
  bf* tblbf = (bf*)(ws + OFF_TBLBF);
  int tid = blockIdx.x * blockDim.x + threadIdx.x;
  int nthr = gridDim.x * blockDim.x;
  for (int i = tid; i < 192 * 576; i += nthr) {
    int k = i / 576, n = i % 576;
    wqkvT[n * 192 + k] = (bf)wqkv[i];
  }
  for (int i = tid; i < 192 * 192; i += nthr) {
    int k = i / 192, n = i % 192;
    woutT[n * 192 + k] = (bf)wout[i];
  }
  for (int i = tid; i < 4 * 49 * 68; i += nthr) {
    int type = i / (49 * 68), rem = i % (49 * 68), r = rem / 68, c = rem % 68;
    float v = 0.0f;
    if (c < 64) {
      if (c < 49) {
        int ix = r / 7, iy = r % 7, jx = c / 7, jy = c % 7;
        v = pos[(jx - ix + 6) * 13 + (jy - iy + 6)];
        if ((type & 1) && ((r >= 28) != (c >= 28))) v += kNEG;  // ul mask
        if ((type & 2) && ((iy >= 4) != (jy >= 4))) v += kNEG;  // lr mask
      } else {
        v = kNEG;  // pad cols -> P==0
      }
    }
    tblbf[i] = (bf)v;
  }
}

// ---------------- K1: QKV GEMM, 1 block = 1 window, 512 thr (8 waves) ----------------
// wave = (mw 0..3, th 0..1): mw -> 48-col n-slice of the current pass, th -> 32-row t-half.
__global__ __launch_bounds__(512, 4) void qkv_kernel(const float* __restrict__ x,
                                                     char* __restrict__ ws) {
  __shared__ __align__(16) bf Xl[49 * X_STRIDE];  // 19600 B

  const bf* wqkvT = (const bf*)(ws + OFF_WQKVT);
  bf* Qg = (bf*)(ws + OFF_QG);
  bf* Kg = (bf*)(ws + OFF_KG);
  bf* VT = (bf*)(ws + OFF_VT);

  int bw = blockIdx.x;
  int b = bw >> 6, win = bw & 63;
  int wh = win >> 3, wwi = win & 7;

  int tid = threadIdx.x;
  int wave = tid >> 6, lane = tid & 63;
  int l15 = lane & 15, g = lane >> 4;
  int mw = wave >> 1, th = wave & 1;

  // stage x window (roll fused) -> LDS bf16
#pragma unroll
  for (int it = 0; it < 3; ++it) {
    int chunk = it * 512 + tid;  // 49 rows * 24 chunks of 8
    if (chunk < 1176) {
      int r = chunk / 24, c8 = (chunk % 24) * 8;
      int tr = r / 7, tc = r % 7;
      int h = wh * 7 + tr + 3; if (h >= 56) h -= 56;
      int w = wwi * 7 + tc + 3; if (w >= 56) w -= 56;
      const float* p = x + (((size_t)b * 56 + h) * 56 + w) * 192 + c8;
      bf16x8 v;
#pragma unroll
      for (int j = 0; j < 8; ++j) v[j] = (bf)p[j];
      *(bf16x8*)(Xl + r * X_STRIDE + c8) = v;
    }
  }
  __syncthreads();

  // B-frag (X rows, t = th*32 + tt*16 + l15) and A-frag (W rows) loads are shared by
  // all three passes; only MFMA operand order and the store layout differ.
#pragma unroll
  for (int pass = 0; pass < 3; ++pass) {
    // pass 0: K (w-cols 192..383, swapped), pass 1: V (384..575, normal), pass 2: Q (0..191, swapped)
    int passBase = (pass == 0) ? 192 : (pass == 1) ? 384 : 0;
    int nbase = passBase + mw * 48;

    f32x4 acc[3][2] = {};
#pragma unroll
    for (int ks = 0; ks < 6; ++ks) {
      bf16x8 xf[2];
#pragma unroll
      for (int tt = 0; tt < 2; ++tt) {
        int t = th * 32 + tt * 16 + l15; if (t > 48) t = 48;  // dup; masked downstream
        xf[tt] = *(const bf16x8*)(Xl + t * X_STRIDE + ks * 32 + g * 8);
      }
#pragma unroll
      for (int nt = 0; nt < 3; ++nt) {
        bf16x8 wf = *(const bf16x8*)(wqkvT + (size_t)(nbase + nt * 16 + l15) * 192 + ks * 32 + g * 8);
#pragma unroll
        for (int tt = 0; tt < 2; ++tt) {
          if (pass == 1) acc[nt][tt] = MFMA16(xf[tt], wf, acc[nt][tt]);  // C[t][n]
          else           acc[nt][tt] = MFMA16(wf, xf[tt], acc[nt][tt]);  // C^T[n][t]
        }
      }
    }

    if (pass == 1) {
      // V: C[t][n]: lane reg r -> t = th*32+tt*16+4g+r, c = mw*48+nt*16+l15.
      // pack 4 consecutive t -> uint2 into VT[bw][c][64] (t 49..63 finite dups, P==0 kills)
#pragma unroll
      for (int nt = 0; nt < 3; ++nt) {
        int c = mw * 48 + nt * 16 + l15;
#pragma unroll
        for (int tt = 0; tt < 2; ++tt) {
          int t4 = th * 32 + tt * 16 + 4 * g;
          uint2 pk;
          pk.x = pack2(acc[nt][tt][0], acc[nt][tt][1]);
          pk.y = pack2(acc[nt][tt][2], acc[nt][tt][3]);
          *(uint2*)(VT + ((size_t)bw * 192 + c) * VT_STR + t4) = pk;
        }
      }
    } else {
      // K/Q: C^T[n][t]: lane reg r -> n = nbase+nt*16+4g+r, t = th*32+tt*16+l15.
      // pack 4 consecutive n -> uint2 into [bw][t][192]
      bf* dstB = (pass == 0) ? Kg : Qg;
#pragma unroll
      for (int nt = 0; nt < 3; ++nt) {
        int c0 = mw * 48 + nt * 16 + 4 * g;   // local col (0..191), 4 consecutive
#pragma unroll
        for (int tt = 0; tt < 2; ++tt) {
          int t = th * 32 + tt * 16 + l15;
          if (t < 49) {
            uint2 pk;
            pk.x = pack2(acc[nt][tt][0], acc[nt][tt][1]);
            pk.y = pack2(acc[nt][tt][2], acc[nt][tt][3]);
            *(uint2*)(dstB + ((size_t)bw * 49 + t) * 192 + c0) = pk;
          }
        }
      }
    }
  }
}

// ---------------- K2: attention, 1 block = 1 (window, head), 128 thr, no LDS ----------------
__global__ __launch_bounds__(128, 6) void attn_kernel(const char* __restrict__ ws) {
  int id = blockIdx.x;
  int bw = id / 6, head = id - bw * 6;
  int win = bw & 63;
  int wh = win >> 3, wwi = win & 7;
  int type = ((wh == 7) ? 1 : 0) | ((wwi == 7) ? 2 : 0);

  const bf* Qh = (const bf*)(ws + OFF_QG) + (size_t)bw * 49 * 192 + head * 32;
  const bf* Kh = (const bf*)(ws + OFF_KG) + (size_t)bw * 49 * 192 + head * 32;
  const bf* Vh = (const bf*)(ws + OFF_VT) + ((size_t)bw * 192 + head * 32) * VT_STR;
  const bf* Tb = (const bf*)(ws + OFF_TBLBF) + type * 49 * 68;
  bf* O2 = (bf*)(ws + OFF_O2) + (size_t)bw * 49 * 192 + head * 32;

  int tid = threadIdx.x;
  int wave = tid >> 6, lane = tid & 63;
  int l15 = lane & 15, g = lane >> 4;

  unsigned pp[2][4][2];
#pragma unroll
  for (int ii = 0; ii < 2; ++ii) {
    int mq = wave * 2 + ii;
    int q = mq * 16 + l15;
    int qc = q > 48 ? 48 : q;
    bf16x8 qf = *(const bf16x8*)(Qh + (size_t)qc * 192 + g * 8);  // B-frag Q[q][d]

    f32x4 sa[4];
#pragma unroll
    for (int T = 0; T < 4; ++T) {
      int kt = ((l15 >> 2) << 3) + ((T & 1) << 2) + ((T >> 1) << 5) + (l15 & 3);
      int ktc = kt > 48 ? 48 : kt;  // dup; killed by NEG bias col
      bf16x8 kf = *(const bf16x8*)(Kh + (size_t)ktc * 192 + g * 8);  // A-frag K[kt][d]
      f32x4 z = {};
      sa[T] = MFMA16(kf, qf, z);
    }

    float e[4][4];
    float lsum = 0.0f;
#pragma unroll
    for (int T = 0; T < 4; ++T) {
      int cb = (g << 3) + ((T & 1) << 2) + ((T >> 1) << 5);
      bf16x4 bias = *(const bf16x4*)(Tb + qc * 68 + cb);
#pragma unroll
      for (int r = 0; r < 4; ++r) {
        float ev = __expf(sa[T][r] * kScale + (float)bias[r]);
        e[T][r] = ev;
        lsum += ev;
      }
    }
    lsum += __shfl_xor(lsum, 16);
    lsum += __shfl_xor(lsum, 32);
    float rinv = 1.0f / lsum;
#pragma unroll
    for (int T = 0; T < 4; ++T) {
      pp[ii][T][0] = pack2(e[T][0] * rinv, e[T][1] * rinv);
      pp[ii][T][1] = pack2(e[T][2] * rinv, e[T][3] * rinv);
    }
  }

  // O = P V : A-frags from pp regs, B-frags from V^T global
#pragma unroll
  for (int ii = 0; ii < 2; ++ii) {
    int mq = wave * 2 + ii;
    f32x4 o0 = {}, o1 = {};
#pragma unroll
    for (int ks = 0; ks < 2; ++ks) {
      union { unsigned u[4]; bf16x8 v; } af;
      af.u[0] = pp[ii][2 * ks][0];
      af.u[1] = pp[ii][2 * ks][1];
      af.u[2] = pp[ii][2 * ks + 1][0];
      af.u[3] = pp[ii][2 * ks + 1][1];
      bf16x8 v0 = *(const bf16x8*)(Vh + (size_t)l15 * VT_STR + ks * 32 + g * 8);
      bf16x8 v1 = *(const bf16x8*)(Vh + (size_t)(16 + l15) * VT_STR + ks * 32 + g * 8);
      o0 = MFMA16(af.v, v0, o0);
      o1 = MFMA16(af.v, v1, o1);
    }
#pragma unroll
    for (int r = 0; r < 4; ++r) {
      int orow = mq * 16 + 4 * g + r;
      if (orow < 49) {
        O2[(size_t)orow * 192 + l15]      = (bf)o0[r];
        O2[(size_t)orow * 192 + 16 + l15] = (bf)o1[r];
      }
    }
  }
}

// ---------------- K3: proj GEMM + bias, 1 block = 1 window, inverse roll on store ----------------
__global__ __launch_bounds__(512, 4) void proj_kernel(const float* __restrict__ bout,
                                                      const char* __restrict__ ws,
                                                      float* __restrict__ out) {
  __shared__ __align__(16) bf Ol[49 * O_STRIDE];  // 19600 B

  const bf* woutT = (const bf*)(ws + OFF_WOUTT);
  const bf* O2 = (const bf*)(ws + OFF_O2);

  int bw = blockIdx.x;
  int b = bw >> 6, win = bw & 63;
  int wh = win >> 3, wwi = win & 7;

  int tid = threadIdx.x;
  int wave = tid >> 6, lane = tid & 63;
  int l15 = lane & 15, g = lane >> 4;
  int mrow = wave >> 2, ncol = wave & 3;

  // stage O2 window -> LDS
#pragma unroll
  for (int it = 0; it < 3; ++it) {
    int chunk = it * 512 + tid;
    if (chunk < 1176) {
      int r = chunk / 24, c8 = (chunk % 24) * 8;
      *(bf16x8*)(Ol + r * O_STRIDE + c8) =
          *(const bf16x8*)(O2 + ((size_t)bw * 49 + r) * 192 + c8);
    }
  }
  __syncthreads();

  f32x4 pacc[2][3] = {};
#pragma unroll
  for (int ks = 0; ks < 6; ++ks) {
    int t0 = mrow * 32 + l15;      if (t0 > 48) t0 = 48;
    int t1 = mrow * 32 + 16 + l15; if (t1 > 48) t1 = 48;
    bf16x8 a0 = *(const bf16x8*)(Ol + t0 * O_STRIDE + ks * 32 + g * 8);
    bf16x8 a1 = *(const bf16x8*)(Ol + t1 * O_STRIDE + ks * 32 + g * 8);
#pragma unroll
    for (int nt = 0; nt < 3; ++nt) {
      bf16x8 bfr = *(const bf16x8*)(woutT + (size_t)(ncol * 48 + nt * 16 + l15) * 192 + ks * 32 + g * 8);
      pacc[0][nt] = MFMA16(a0, bfr, pacc[0][nt]);
      pacc[1][nt] = MFMA16(a1, bfr, pacc[1][nt]);
    }
  }
#pragma unroll
  for (int nt = 0; nt < 3; ++nt) {
    int col = ncol * 48 + nt * 16 + l15;
    float bo = bout[col];
#pragma unroll
    for (int mt = 0; mt < 2; ++mt) {
#pragma unroll
      for (int r = 0; r < 4; ++r) {
        int t = mrow * 32 + mt * 16 + 4 * g + r;
        if (t < 49) {
          int tr = t / 7, tc = t % 7;
          int h = wh * 7 + tr + 3; if (h >= 56) h -= 56;
          int w2 = wwi * 7 + tc + 3; if (w2 >= 56) w2 -= 56;
          out[(((size_t)b * 56 + h) * 56 + w2) * 192 + col] = pacc[mt][nt][r] + bo;
        }
      }
    }
  }
}

extern "C" void kernel_launch(void* const* d_in, const int* in_sizes, int n_in,
                              void* d_out, int out_size, void* d_ws, size_t ws_size,
                              hipStream_t stream) {
  const float* x = (const float*)d_in[0];
  const float* wqkv = (const float*)d_in[1];
  const float* wout = (const float*)d_in[2];
  const float* bout = (const float*)d_in[3];
  const float* pos = (const float*)d_in[4];
  char* ws = (char*)d_ws;

  hipLaunchKernelGGL(prep_kernel, dim3(128), dim3(256), 0, stream, wqkv, wout, pos, ws);
  hipLaunchKernelGGL(qkv_kernel, dim3(2048), dim3(512), 0, stream, x, ws);
  hipLaunchKernelGGL(attn_kernel, dim3(12288), dim3(128), 0, stream, (const char*)ws);
  hipLaunchKernelGGL(proj_kernel, dim3(2048), dim3(512), 0, stream, bout, (const char*)ws, (float*)d_out);
}